// Round 5
// baseline (675.050 us; speedup 1.0000x reference)
//
#include <hip/hip_runtime.h>
#include <math.h>

typedef unsigned short u16;
typedef __attribute__((ext_vector_type(8))) short bf16x8;
typedef __attribute__((ext_vector_type(4))) float f32x4;
typedef const __attribute__((address_space(1))) unsigned int* gas_t;
typedef __attribute__((address_space(3))) unsigned int* las_t;

__device__ __forceinline__ float bf2f(u16 u) {
    unsigned x = ((unsigned)u) << 16; float f; __builtin_memcpy(&f, &x, 4); return f;
}
__device__ __forceinline__ u16 f2bf(float f) {
    unsigned x; __builtin_memcpy(&x, &f, 4);
    unsigned lsb = (x >> 16) & 1u; x += 0x7fffu + lsb; return (u16)(x >> 16);
}

// ---------------- input dtype detector (1 = f32 inputs) ----------------
__global__ __launch_bounds__(256) void k_detect(const u16* __restrict__ wq, int* __restrict__ flag) {
    const int tid = threadIdx.x;
    int cnt = 0;
    for (int i = tid; i < 2048; i += 256) {
        float v = fabsf(bf2f(wq[2 * i]));
        if (!(v < 1e4f) || (v != 0.f && v < 1e-30f)) cnt++;
    }
    for (int off = 32; off; off >>= 1) cnt += __shfl_down(cnt, off, 64);
    __shared__ int red[4];
    int lane = tid & 63, w = tid >> 6;
    if (!lane) red[w] = cnt;
    __syncthreads();
    if (!tid) flag[0] = (red[0] + red[1] + red[2] + red[3] > 204) ? 1 : 0;
}

// ---------------- small-vector convert: [bqkv|bgate|bproj|lng|lnb] -> bf16 ----------------
__global__ __launch_bounds__(256) void k_cvec(const void* __restrict__ bqkv, const void* __restrict__ bgate,
                                              const void* __restrict__ bproj, const void* __restrict__ lng,
                                              const void* __restrict__ lnb, const int* __restrict__ flag,
                                              u16* __restrict__ cv) {
    int i = blockIdx.x * 256 + threadIdx.x;   // 0..7167
    const void* src; int off;
    if (i < 3072)      { src = bqkv;  off = i; }
    else if (i < 4096) { src = bgate; off = i - 3072; }
    else if (i < 5120) { src = bproj; off = i - 4096; }
    else if (i < 6144) { src = lng;   off = i - 5120; }
    else               { src = lnb;   off = i - 6144; }
    cv[i] = flag[0] ? f2bf(((const float*)src)[off]) : ((const u16*)src)[off];
}

#define ZERO_ACC8(acc) \
    _Pragma("unroll") for (int mi = 0; mi < 8; ++mi) \
    _Pragma("unroll") for (int ni = 0; ni < 4; ++ni) acc[mi][ni] = (f32x4){0.f, 0.f, 0.f, 0.f};

// ---------------- 256x256-tile FREE-RUN K-loop (T2 swizzle + counted vmcnt) ----------------
// 512 threads = 8 waves (2M x 4N); per-wave C = 128x64. BK=64 (2 MFMA k-slices).
// LDS 128KB (u16 units): A dbuf = parity*16384 + half*8192, B same at +32768.
// XOR swizzle (involution, rule #21): LDS written LINEARLY by global_load_lds; per-lane GLOBAL
// source col-group is pre-XORed with (row&7); ds_read applies the same XOR -> conflict-free b128.
// r5 STRUCTURE: intra-tile barriers removed. Within tile t all waves ONLY READ buffer p
// (t+1 was staged into buffer q at tile t-1) -> no intra-tile hazard. Per tile:
//   [24 ds_read_b128 + 64 MFMA, free-run; compiler interleaves, wave skew overlaps
//    one wave's LDS reads with another's MFMAs]
//   barrier1   (all waves' reads of p retired -- MFMA consumption forces the waitcnts)
//   stage FULL tile t+2 into p (WAR-safe now); vmcnt(8) retires t+1 (FIFO, m135)
//   barrier2   (publishes t+1 residency to all waves)
// 2 barriers/tile vs 8 in the lockstep schedule. vmcnt asm carries "memory" clobber so the
// compiler cannot hoist next-tile ds_reads above the residency wait.
__device__ __forceinline__ void gemm256_loop(const u16* __restrict__ Ab, long ar0, long lda, long ka0,
                                             const u16* __restrict__ Bb, long br0, long ldb, long kb0,
                                             int ktiles, u16* lds, int tid, f32x4 acc[8][4]) {
    const int lane = tid & 63, wave = tid >> 6;
    const int waveM = wave >> 2, waveN = wave & 3;
    const int l16 = lane & 15, quad = lane >> 4;
    const int x = l16 & 7;
    const long sT = (long)(((tid & 7) ^ ((tid >> 3) & 7)) << 3);   // pre-swizzled slot (elements)
    const u16* sA = Ab + (ar0 + (tid >> 3)) * lda + ka0 + sT;
    const u16* sB = Bb + (br0 + (tid >> 3)) * ldb + kb0 + sT;
    u16* const ldsw = lds + wave * 512;
    // hoisted per-lane read bases (u16-element units)
    const int s0 = (quad ^ x) << 3;
    const int s1 = s0 ^ 32;
    const int aB0 = waveM * 8192 + l16 * 64 + s0;
    const int aB1 = waveM * 8192 + l16 * 64 + s1;
    const int bB0 = 32768 + (waveN >> 1) * 8192 + ((waveN & 1) * 64 + l16) * 64 + s0;
    const int bB1 = 32768 + (waveN >> 1) * 8192 + ((waveN & 1) * 64 + l16) * 64 + s1;

#define STG_A(p, mh, t) do { \
        const u16* g_ = sA + ((long)((mh) * 128)) * lda + (long)(t) * 64; \
        __builtin_amdgcn_global_load_lds((gas_t)g_, (las_t)(ldsw + (p) * 16384 + (mh) * 8192), 16, 0, 0); \
        __builtin_amdgcn_global_load_lds((gas_t)(g_ + 64 * lda), (las_t)(ldsw + (p) * 16384 + (mh) * 8192 + 4096), 16, 0, 0); \
    } while (0)
#define STG_B(p, nh, t) do { \
        const u16* g_ = sB + ((long)((nh) * 128)) * ldb + (long)(t) * 64; \
        __builtin_amdgcn_global_load_lds((gas_t)g_, (las_t)(ldsw + 32768 + (p) * 16384 + (nh) * 8192), 16, 0, 0); \
        __builtin_amdgcn_global_load_lds((gas_t)(g_ + 64 * ldb), (las_t)(ldsw + 32768 + (p) * 16384 + (nh) * 8192 + 4096), 16, 0, 0); \
    } while (0)
#define RD_A(mi_, ks_) (*(const bf16x8*)(lds + pb + ((ks_) ? aB1 : aB0) + (mi_) * 1024))
#define RD_B(ni_, ks_) (*(const bf16x8*)(lds + pb + ((ks_) ? bB1 : bB0) + (ni_) * 1024))

    // prologue: tile0 + tile1 fully staged; vmcnt(8) -> tile0 resident, tile1's 8 in flight
    STG_A(0, 0, 0); STG_A(0, 1, 0); STG_B(0, 0, 0); STG_B(0, 1, 0);
    if (ktiles > 1) {
        STG_A(1, 0, 1); STG_A(1, 1, 1); STG_B(1, 0, 1); STG_B(1, 1, 1);
        asm volatile("s_waitcnt vmcnt(8)" ::: "memory");
    } else {
        asm volatile("s_waitcnt vmcnt(0)" ::: "memory");
    }
    __builtin_amdgcn_s_barrier();

    for (int t = 0; t < ktiles; ++t) {
        const int p = t & 1;
        const int pb = p * 16384;
        // ---- free-run region: all fragment reads + all MFMAs of tile t (buffer p) ----
        bf16x8 aF[8][2], bF[4][2];
#pragma unroll
        for (int mi = 0; mi < 8; ++mi)
#pragma unroll
            for (int ks = 0; ks < 2; ++ks) aF[mi][ks] = RD_A(mi, ks);
#pragma unroll
        for (int ni = 0; ni < 4; ++ni)
#pragma unroll
            for (int ks = 0; ks < 2; ++ks) bF[ni][ks] = RD_B(ni, ks);
#pragma unroll
        for (int mi = 0; mi < 8; ++mi)
#pragma unroll
            for (int ni = 0; ni < 4; ++ni)
#pragma unroll
                for (int ks = 0; ks < 2; ++ks)
                    acc[mi][ni] = __builtin_amdgcn_mfma_f32_16x16x32_bf16(aF[mi][ks], bF[ni][ks], acc[mi][ni], 0, 0, 0);
        // ---- barrier1: every wave's reads of buffer p are retired (consumed by MFMA) ----
        __builtin_amdgcn_s_barrier();
        if (t + 2 < ktiles) {
            STG_A(p, 0, t + 2); STG_A(p, 1, t + 2);
            STG_B(p, 0, t + 2); STG_B(p, 1, t + 2);
            asm volatile("s_waitcnt vmcnt(8)" ::: "memory");   // retires tile t+1's 8 loads
        } else if (t + 1 < ktiles) {
            asm volatile("s_waitcnt vmcnt(0)" ::: "memory");
        }
        if (t + 1 < ktiles) __builtin_amdgcn_s_barrier();      // barrier2: t+1 resident for all
    }
#undef STG_A
#undef STG_B
#undef RD_A
#undef RD_B
}

// ---------------- tiled weight transpose (coalesced reads) ----------------
__global__ __launch_bounds__(256) void k_transw(const void* __restrict__ wqkv, const void* __restrict__ wgate,
                                                const void* __restrict__ wproj, const int* __restrict__ flag,
                                                u16* __restrict__ Wt, u16* __restrict__ WpT) {
    const int bid = blockIdx.x, tid = threadIdx.x;   // 1280 blocks: 80 n-tiles x 16 k-tiles
    const int ktl = bid & 15, ntile = bid >> 4;
    const int n0 = ntile * 64, k0 = ktl * 64;
    const int fl = flag[0];
    const void* src; int ld, c0;
    if (n0 < 3072)      { src = wqkv;  ld = 3072; c0 = n0; }
    else if (n0 < 4096) { src = wgate; ld = 1024; c0 = n0 - 3072; }
    else                { src = wproj; ld = 1024; c0 = n0 - 4096; }
    __shared__ u16 t[64][66];
#pragma unroll
    for (int i = 0; i < 16; ++i) {
        int idx = tid + i * 256; int r = idx >> 6, c = idx & 63;   // r=k, c=n (local)
        long off = (long)(k0 + r) * ld + c0 + c;
        float v = fl ? ((const float*)src)[off] : bf2f(((const u16*)src)[off]);
        t[r][c] = f2bf(v);
    }
    __syncthreads();
#pragma unroll
    for (int i = 0; i < 16; ++i) {
        int idx = tid + i * 256; int r = idx >> 6, c = idx & 63;   // r=n, c=k (local)
        int n = n0 + r;
        if (n < 4096) Wt[(long)n * 1024 + k0 + c] = t[c][r];
        else          WpT[(long)(n - 4096) * 1024 + k0 + c] = t[c][r];
    }
}

// ---------------- LayerNorm ----------------
__global__ __launch_bounds__(256) void k_ln(const void* __restrict__ xin, const u16* __restrict__ cv,
                                            const int* __restrict__ flag, u16* __restrict__ XN) {
    const long t = blockIdx.x; const int tid = threadIdx.x;
    const int fl = flag[0];
    float v[4], s = 0.f, sq = 0.f;
#pragma unroll
    for (int i = 0; i < 4; ++i) {
        long a = t * 1024 + tid + i * 256;
        v[i] = fl ? ((const float*)xin)[a] : bf2f(((const u16*)xin)[a]);
        s += v[i]; sq += v[i] * v[i];
    }
    for (int off = 32; off; off >>= 1) { s += __shfl_down(s, off, 64); sq += __shfl_down(sq, off, 64); }
    __shared__ float red[8];
    int lane = tid & 63, w = tid >> 6;
    if (!lane) { red[w] = s; red[4 + w] = sq; }
    __syncthreads();
    float S = red[0] + red[1] + red[2] + red[3];
    float SQ = red[4] + red[5] + red[6] + red[7];
    float mu = S * (1.f / 1024.f);
    float var = SQ * (1.f / 1024.f) - mu * mu;
    float rs = rsqrtf(var + 1e-5f);
#pragma unroll
    for (int i = 0; i < 4; ++i) {
        int col = tid + i * 256;
        XN[t * 1024 + col] = f2bf((v[i] - mu) * rs * bf2f(cv[5120 + col]) + bf2f(cv[6144 + col]));
    }
}

// ---------------- GEMM1 (256^2 free-run): [q|k|v|gate] = XN @ Wt^T + bias ----------------
// grid 1024 = 64 mt x 16 nt; group = nt>>2: 0=q(elu+1) 1=k 2=v(transposed) 3=gate
__global__ __launch_bounds__(512, 2) void k_gemm1(const u16* __restrict__ XN, const u16* __restrict__ Wt,
                                                  const u16* __restrict__ cv,
                                                  u16* __restrict__ Q, u16* __restrict__ K,
                                                  u16* __restrict__ G, u16* __restrict__ vT) {
    __shared__ u16 lds[65536];   // 128KB: K-loop dbuf; reused as [64][264] transpose staging for v
    const int tid = threadIdx.x;
    const int swz = ((blockIdx.x & 7) << 7) | (blockIdx.x >> 3);   // bijective XCD swizzle (1024%8==0)
    const int nt = swz & 15, mt = swz >> 4;
    f32x4 acc[8][4]; ZERO_ACC8(acc);
    gemm256_loop(XN, (long)mt * 256, 1024, 0, Wt, (long)nt * 256, 1024, 0, 16, lds, tid, acc);
    const int lane = tid & 63, wave = tid >> 6;
    const int waveM = wave >> 2, waveN = wave & 3;
    const int l16 = lane & 15, quad = lane >> 4;
    const int g = nt >> 2;
    if (g == 2) {              // v: stage [col][264] in LDS, write t-contiguous to vT[b][d][t]
        const int b = mt >> 4;
        const long tb0 = (long)(mt & 15) * 256;
#pragma unroll
        for (int h = 0; h < 4; ++h) {
            if (waveN == h) {
#pragma unroll
                for (int mi = 0; mi < 8; ++mi)
#pragma unroll
                    for (int ni = 0; ni < 4; ++ni) {
                        int col = ni * 16 + l16;
                        float bias = bf2f(cv[nt * 256 + h * 64 + col]);
#pragma unroll
                        for (int r = 0; r < 4; ++r)
                            lds[col * 264 + waveM * 128 + mi * 16 + quad * 4 + r] = f2bf(acc[mi][ni][r] + bias);
                    }
            }
            __syncthreads();
#pragma unroll
            for (int i = 0; i < 4; ++i) {
                int c = tid + i * 512;                  // 2048 chunks of 8 u16
                int col = c >> 5, t8 = (c & 31) * 8;
                uint4 val = *(const uint4*)(lds + col * 264 + t8);
                long dg = (long)(nt & 3) * 256 + h * 64 + col;
                *(uint4*)(vT + (long)b * 4194304 + dg * 4096 + tb0 + t8) = val;
            }
            __syncthreads();
        }
    } else {
        u16* dst = (g == 0) ? Q : (g == 1) ? K : G;
#pragma unroll
        for (int mi = 0; mi < 8; ++mi)
#pragma unroll
            for (int ni = 0; ni < 4; ++ni) {
                int colg = nt * 256 + waveN * 64 + ni * 16 + l16;
                int d = colg & 1023;
                float bias = bf2f(cv[colg]);
                long row0 = (long)mt * 256 + waveM * 128 + mi * 16 + quad * 4;
#pragma unroll
                for (int r = 0; r < 4; ++r) {
                    float v = acc[mi][ni][r] + bias;
                    if (g == 0) v = v > 0.f ? v + 1.f : expf(v);   // elu(q)+1 fused, f32
                    dst[(row0 + r) * 1024 + d] = f2bf(v);
                }
            }
    }
}

// ---------------- k = elu(k_raw * sigmoid(gate)) + 1, in place ----------------
__global__ __launch_bounds__(256) void k_act(u16* __restrict__ K, const u16* __restrict__ G) {
    const long t = blockIdx.x; const int tid = threadIdx.x;
#pragma unroll
    for (int i = 0; i < 4; ++i) {
        long a = t * 1024 + tid + i * 256;
        float kk = bf2f(K[a]) / (1.f + expf(-bf2f(G[a])));
        kk = kk > 0.f ? kk + 1.f : expf(kk);
        K[a] = f2bf(kk);
    }
}

// ---------------- tiled transpose: kT[b][d][t] <- K[t][d] ----------------
__global__ __launch_bounds__(256) void k_transk(const u16* __restrict__ K, u16* __restrict__ kT) {
    const int bid = blockIdx.x, tid = threadIdx.x;   // 256 tt x 16 dt
    const int dt = bid & 15, tt = bid >> 4;
    __shared__ u16 tileS[64][65];
#pragma unroll
    for (int i = 0; i < 16; ++i) {
        int idx = tid + i * 256; int r = idx >> 6, cc = idx & 63;
        tileS[r][cc] = K[(long)(tt * 64 + r) * 1024 + dt * 64 + cc];
    }
    __syncthreads();
    long tg = (long)tt * 64; int b = (int)(tg >> 12); long tb = tg & 4095;
#pragma unroll
    for (int i = 0; i < 16; ++i) {
        int idx = tid + i * 256; int r = idx >> 6, cc = idx & 63;
        kT[(long)b * 4194304 + (long)(dt * 64 + r) * 4096 + tb + cc] = tileS[cc][r];
    }
}

// ---------------- per-chunk k sums: csum[b][c][d] ----------------
__global__ __launch_bounds__(256) void k_csum(const u16* __restrict__ K, float* __restrict__ csum) {
    const int bid = blockIdx.x, tid = threadIdx.x;   // 64 blocks
    const int b = bid >> 4, c = (bid >> 2) & 3, dg = bid & 3;
    const int d = dg * 256 + tid;
    const u16* base = K + ((long)b * 4096 + c * 1024) * 1024 + d;
    float s = 0.f;
    for (int t = 0; t < 1024; ++t) s += bf2f(base[(long)t * 1024]);
    csum[((b * 4 + c) << 10) + d] = s;
}

// ---------------- pass1 (256^2 free-run): ST[b][c][d][e] = sum_s v[s,d] k[s,e] ----------------
// grid 256 = 16 bc (LOW bits -> same-bc blocks share an XCD L2) x 16 tiles(4dt x 4et)
__global__ __launch_bounds__(512, 2) void k_pass1(const u16* __restrict__ kT, const u16* __restrict__ vT,
                                                  u16* __restrict__ ST) {
    __shared__ u16 lds[65536];
    const int tid = threadIdx.x, bid = blockIdx.x;
    const int bc = bid & 15, tile = bid >> 4;
    const int dt = tile >> 2, et = tile & 3;
    const int c = bc & 3, b = bc >> 2;
    f32x4 acc[8][4]; ZERO_ACC8(acc);
    gemm256_loop(vT + (long)b * 4194304, (long)dt * 256, 4096, (long)c * 1024,
                 kT + (long)b * 4194304, (long)et * 256, 4096, (long)c * 1024, 16, lds, tid, acc);
    const int lane = tid & 63, wave = tid >> 6;
    const int waveM = wave >> 2, waveN = wave & 3;
    const int l16 = lane & 15, quad = lane >> 4;
    u16* dst = ST + ((long)(b * 4 + c) << 20);
#pragma unroll
    for (int mi = 0; mi < 8; ++mi)
#pragma unroll
        for (int ni = 0; ni < 4; ++ni) {
            long e = et * 256 + waveN * 64 + ni * 16 + l16;
            long d0 = dt * 256 + waveM * 128 + mi * 16 + quad * 4;
#pragma unroll
            for (int r = 0; r < 4; ++r)
                dst[(d0 + r) * 1024 + e] = f2bf(acc[mi][ni][r]);
        }
}

// ---------------- in-place exclusive prefix over chunk states ----------------
__global__ __launch_bounds__(256) void k_stpre(u16* __restrict__ ST) {
    const long gid = (long)blockIdx.x * 256 + threadIdx.x;  // 4M
    const int b = (int)(gid >> 20); const long rem = gid & 0xFFFFF;
    float run = 0.f;
    for (int c = 0; c < 4; ++c) {
        long a = (((long)(b * 4 + c)) << 20) + rem;
        float v = bf2f(ST[a]);
        ST[a] = f2bf(run);
        run += v;
    }
}

// ---------------- pass2a (256^2 free-run): P[t, s_local] = masked q_t . k_s (intra chunk) ----
// grid 256 = 16 bc x 16 tiles(4tt x 4ss); ss>tt tiles are zero-filled
__global__ __launch_bounds__(512, 2) void k_pass2a(const u16* __restrict__ Q, const u16* __restrict__ K,
                                                   u16* __restrict__ P) {
    __shared__ u16 lds[65536];
    const int tid = threadIdx.x, bid = blockIdx.x;
    const int bc = bid & 15, tile = bid >> 4;
    const int tt = tile >> 2, ss = tile & 3;
    const int c = bc & 3, b = bc >> 2;
    const long trow0 = (long)b * 4096 + c * 1024 + tt * 256;
    if (ss > tt) {   // strictly-upper 256x256 tile: zeros (block-uniform)
#pragma unroll
        for (int i = 0; i < 16; ++i) {
            int ch = tid + i * 512;                 // 8192 chunks of 8 u16
            int row = ch >> 5, col8 = (ch & 31) * 8;
            *(uint4*)(P + (trow0 + row) * 1024 + ss * 256 + col8) = (uint4){0u, 0u, 0u, 0u};
        }
        return;
    }
    const long srow0 = (long)b * 4096 + c * 1024 + ss * 256;
    f32x4 acc[8][4]; ZERO_ACC8(acc);
    gemm256_loop(Q, trow0, 1024, 0, K, srow0, 1024, 0, 16, lds, tid, acc);
    const int lane = tid & 63, wave = tid >> 6;
    const int waveM = wave >> 2, waveN = wave & 3;
    const int l16 = lane & 15, quad = lane >> 4;
    const int diag = (ss == tt);
#pragma unroll
    for (int mi = 0; mi < 8; ++mi)
#pragma unroll
        for (int ni = 0; ni < 4; ++ni) {
            int slc = waveN * 64 + ni * 16 + l16;
#pragma unroll
            for (int r = 0; r < 4; ++r) {
                int tl = waveM * 128 + mi * 16 + quad * 4 + r;
                float v = (!diag || tl >= slc) ? acc[mi][ni][r] : 0.f;
                P[(trow0 + tl) * 1024 + ss * 256 + slc] = f2bf(v);
            }
        }
}

// ---------------- den[t] = q_t . chunk_prefix + rowsum(P) + eps ----------------
__global__ __launch_bounds__(256) void k_den(const u16* __restrict__ Q, const u16* __restrict__ P,
                                             const float* __restrict__ csum, float* __restrict__ den) {
    const long t = blockIdx.x; const int tid = threadIdx.x;
    const int b = (int)(t >> 12), c = (int)((t >> 10) & 3);
    float s = 0.f;
#pragma unroll
    for (int i = 0; i < 4; ++i) {
        int e = tid + i * 256;
        float kp = 0.f;
        for (int cp = 0; cp < c; ++cp) kp += csum[((b * 4 + cp) << 10) + e];
        s += bf2f(Q[t * 1024 + e]) * kp + bf2f(P[t * 1024 + e]);
    }
    for (int off = 32; off; off >>= 1) s += __shfl_down(s, off, 64);
    __shared__ float red[4];
    int lane = tid & 63, w = tid >> 6;
    if (!lane) red[w] = s;
    __syncthreads();
    if (!tid) den[t] = red[0] + red[1] + red[2] + red[3] + 1e-6f;
}

// ---------------- pass2b (256^2 free-run): y[t,d] = (q@ST_prefix + P@V)/den ----------------
// grid 256 = 16 bc x 16 tiles(4tt x 4dd)
__global__ __launch_bounds__(512, 2) void k_pass2b(const u16* __restrict__ Q, const u16* __restrict__ ST,
                                                   const u16* __restrict__ P, const u16* __restrict__ vT,
                                                   const float* __restrict__ den, u16* __restrict__ Yb) {
    __shared__ u16 lds[65536];
    const int tid = threadIdx.x, bid = blockIdx.x;
    const int bc = bid & 15, tile = bid >> 4;
    const int tt = tile >> 2, dd = tile & 3;
    const int c = bc & 3, b = bc >> 2;
    const long trow0 = (long)b * 4096 + c * 1024 + tt * 256;
    f32x4 acc[8][4]; ZERO_ACC8(acc);
    if (c > 0)  // inter-chunk (prefix is zero for c==0); block-uniform branch
        gemm256_loop(Q, trow0, 1024, 0, ST + ((long)(b * 4 + c) << 20), (long)dd * 256, 1024, 0,
                     16, lds, tid, acc);
    // intra-chunk: P upper region zeroed, so full tiles up to (tt+1)*256 of s are correct
    gemm256_loop(P, trow0, 1024, 0, vT + (long)b * 4194304, (long)dd * 256, 4096, (long)c * 1024,
                 (tt + 1) * 4, lds, tid, acc);
    const int lane = tid & 63, wave = tid >> 6;
    const int waveM = wave >> 2, waveN = wave & 3;
    const int l16 = lane & 15, quad = lane >> 4;
#pragma unroll
    for (int mi = 0; mi < 8; ++mi)
#pragma unroll
        for (int ni = 0; ni < 4; ++ni) {
            long d = dd * 256 + waveN * 64 + ni * 16 + l16;
#pragma unroll
            for (int r = 0; r < 4; ++r) {
                long t = trow0 + waveM * 128 + mi * 16 + quad * 4 + r;
                Yb[t * 1024 + d] = f2bf(acc[mi][ni][r] / den[t]);
            }
        }
}

// ---------------- proj (256^2 free-run): out = y @ w_proj + b_proj (dtype-aware store) ----------------
// grid 256 = 64 mt x 4 nt
__global__ __launch_bounds__(512, 2) void k_proj(const u16* __restrict__ Yb, const u16* __restrict__ WpT,
                                                 const u16* __restrict__ cv, const int* __restrict__ flag,
                                                 void* __restrict__ out) {
    __shared__ u16 lds[65536];
    const int tid = threadIdx.x, bid = blockIdx.x;
    const int nt = bid & 3, mt = bid >> 2;
    f32x4 acc[8][4]; ZERO_ACC8(acc);
    gemm256_loop(Yb, (long)mt * 256, 1024, 0, WpT, (long)nt * 256, 1024, 0, 16, lds, tid, acc);
    const int lane = tid & 63, wave = tid >> 6;
    const int waveM = wave >> 2, waveN = wave & 3;
    const int l16 = lane & 15, quad = lane >> 4;
    const int fl = flag[0];
#pragma unroll
    for (int mi = 0; mi < 8; ++mi)
#pragma unroll
        for (int ni = 0; ni < 4; ++ni) {
            long col = nt * 256 + waveN * 64 + ni * 16 + l16;
            float bias = bf2f(cv[4096 + col]);
            long row0 = (long)mt * 256 + waveM * 128 + mi * 16 + quad * 4;
#pragma unroll
            for (int r = 0; r < 4; ++r) {
                float v = acc[mi][ni][r] + bias;
                if (fl) ((float*)out)[(row0 + r) * 1024 + col] = v;
                else    ((u16*)out)[(row0 + r) * 1024 + col] = f2bf(v);
            }
        }
}

// ---------------- fallback: report ws_size via output constant ----------------
__global__ __launch_bounds__(256) void k_fb(u16* __restrict__ out, long n, float val) {
    long i = (long)blockIdx.x * 256 + threadIdx.x;
    if (i < n) out[i] = f2bf(val);
}

extern "C" void kernel_launch(void* const* d_in, const int* in_sizes, int n_in,
                              void* d_out, int out_size, void* d_ws, size_t ws_size,
                              hipStream_t stream) {
    const void* x     = d_in[0];
    const void* wqkv  = d_in[1];
    const void* bqkv  = d_in[2];
    const void* wgate = d_in[3];
    const void* bgate = d_in[4];
    const void* wproj = d_in[5];
    const void* bproj = d_in[6];
    const void* lng   = d_in[7];
    const void* lnb   = d_in[8];

    const long NEEDED = 178403336L;   // ~170.1 MB
    if (ws_size < (size_t)NEEDED) {
        k_fb<<<(int)((out_size + 255) / 256), 256, 0, stream>>>((u16*)d_out, out_size, (float)(ws_size >> 20));
        return;
    }

    char* w = (char*)d_ws;
    u16* XN  = (u16*)(w);                 // 32MB [16384,1024]; dead after gemm1
    u16* ST  = XN;                        // 32MB [16][1024][1024] (alias)
    u16* Q   = (u16*)(w + 33554432L);     // 32MB (elu(q)+1)
    u16* K   = (u16*)(w + 67108864L);     // 32MB; dead after pass2a
    u16* Yb  = K;                         // 32MB (alias)
    u16* G   = (u16*)(w + 100663296L);    // 32MB gate; dead after act
    u16* kT  = G;                         // (alias); dead after pass1
    u16* P   = G;                         // (alias)
    u16* vT  = (u16*)(w + 134217728L);    // 32MB [4][1024][4096]
    u16* Wt  = (u16*)(w + 167772160L);    // 8MB  [4096,1024]
    u16* WpT = (u16*)(w + 176160768L);    // 2MB  [1024,1024]
    float* csum = (float*)(w + 178257920L);  // 64KB [16][1024]
    float* den  = (float*)(w + 178323456L);  // 64KB [16384]
    u16* cv     = (u16*)(w + 178388992L);    // 14KB
    int* flag   = (int*)(w + 178403328L);    // 4B

    k_detect<<<1,     256, 0, stream>>>((const u16*)wqkv, flag);
    k_cvec  <<<28,    256, 0, stream>>>(bqkv, bgate, bproj, lng, lnb, flag, cv);
    k_transw<<<1280,  256, 0, stream>>>(wqkv, wgate, wproj, flag, Wt, WpT);
    k_ln    <<<16384, 256, 0, stream>>>(x, cv, flag, XN);
    k_gemm1 <<<1024,  512, 0, stream>>>(XN, Wt, cv, Q, K, G, vT);
    k_act   <<<16384, 256, 0, stream>>>(K, G);
    k_transk<<<4096,  256, 0, stream>>>(K, kT);
    k_csum  <<<64,    256, 0, stream>>>(K, csum);
    k_pass1 <<<256,   512, 0, stream>>>(kT, vT, ST);
    k_stpre <<<16384, 256, 0, stream>>>(ST);
    k_pass2a<<<256,   512, 0, stream>>>(Q, K, P);
    k_den   <<<16384, 256, 0, stream>>>(Q, P, csum, den);
    k_pass2b<<<256,   512, 0, stream>>>(Q, ST, P, vT, den, Yb);
    k_proj  <<<256,   512, 0, stream>>>(Yb, WpT, cv, flag, d_out);
}

// Round 6
// 539.646 us; speedup vs baseline: 1.2509x; 1.2509x over previous
//
#include <hip/hip_runtime.h>
#include <math.h>

typedef unsigned short u16;
typedef __attribute__((ext_vector_type(8))) short bf16x8;
typedef __attribute__((ext_vector_type(4))) float f32x4;
typedef const __attribute__((address_space(1))) unsigned int* gas_t;
typedef __attribute__((address_space(3))) unsigned int* las_t;

__device__ __forceinline__ float bf2f(u16 u) {
    unsigned x = ((unsigned)u) << 16; float f; __builtin_memcpy(&f, &x, 4); return f;
}
__device__ __forceinline__ u16 f2bf(float f) {
    unsigned x; __builtin_memcpy(&x, &f, 4);
    unsigned lsb = (x >> 16) & 1u; x += 0x7fffu + lsb; return (u16)(x >> 16);
}

// ---------------- input dtype detector (1 = f32 inputs) ----------------
__global__ __launch_bounds__(256) void k_detect(const u16* __restrict__ wq, int* __restrict__ flag) {
    const int tid = threadIdx.x;
    int cnt = 0;
    for (int i = tid; i < 2048; i += 256) {
        float v = fabsf(bf2f(wq[2 * i]));
        if (!(v < 1e4f) || (v != 0.f && v < 1e-30f)) cnt++;
    }
    for (int off = 32; off; off >>= 1) cnt += __shfl_down(cnt, off, 64);
    __shared__ int red[4];
    int lane = tid & 63, w = tid >> 6;
    if (!lane) red[w] = cnt;
    __syncthreads();
    if (!tid) flag[0] = (red[0] + red[1] + red[2] + red[3] > 204) ? 1 : 0;
}

// ------- small-vector convert: [bqkv|bgate|bproj|lng|lnb] -> bf16 ; also zeroes csum -------
__global__ __launch_bounds__(256) void k_cvec(const void* __restrict__ bqkv, const void* __restrict__ bgate,
                                              const void* __restrict__ bproj, const void* __restrict__ lng,
                                              const void* __restrict__ lnb, const int* __restrict__ flag,
                                              u16* __restrict__ cv, float* __restrict__ csum) {
    int i = blockIdx.x * 256 + threadIdx.x;   // 0..23551
    if (i >= 7168) {                           // tail: zero csum[16384]
        int j = i - 7168;
        if (j < 16384) csum[j] = 0.f;
        return;
    }
    const void* src; int off;
    if (i < 3072)      { src = bqkv;  off = i; }
    else if (i < 4096) { src = bgate; off = i - 3072; }
    else if (i < 5120) { src = bproj; off = i - 4096; }
    else if (i < 6144) { src = lng;   off = i - 5120; }
    else               { src = lnb;   off = i - 6144; }
    cv[i] = flag[0] ? f2bf(((const float*)src)[off]) : ((const u16*)src)[off];
}

#define ZERO_ACC8(acc) \
    _Pragma("unroll") for (int mi = 0; mi < 8; ++mi) \
    _Pragma("unroll") for (int ni = 0; ni < 4; ++ni) acc[mi][ni] = (f32x4){0.f, 0.f, 0.f, 0.f};

// ---------------- 256x256-tile 8-phase K-loop (round-4 measured best: T2 swizzle +
// T3/T4 counted vmcnt + T5 setprio; fine per-phase ds_read || stage || MFMA interleave) ----
// 512 threads = 8 waves (2M x 4N); per-wave C = 128x64. BK=64 (2 MFMA k-slices).
// LDS 128KB (u16 units): A dbuf = parity*16384 + half*8192, B same at +32768.
// XOR swizzle (involution, rule #21): LDS written LINEARLY by global_load_lds; per-lane GLOBAL
// source col-group is pre-XORed with (row&7); ds_read applies the same XOR -> conflict-free b128.
// Staging schedule: P1:(t+1,B1) P2:(t+1,A1) P3:(t+2,A0) P4:(t+2,B0); every slot's overwrite
// issued >=1 barrier after its last drained read. Counted vmcnt(4) once per tile at P4 retires
// exactly tile t+1's 8 loads -- never drains to 0 in steady state.
__device__ __forceinline__ void gemm256_loop(const u16* __restrict__ Ab, long ar0, long lda, long ka0,
                                             const u16* __restrict__ Bb, long br0, long ldb, long kb0,
                                             int ktiles, u16* lds, int tid, f32x4 acc[8][4]) {
    const int lane = tid & 63, wave = tid >> 6;
    const int waveM = wave >> 2, waveN = wave & 3;
    const int l16 = lane & 15, quad = lane >> 4;
    const int x = l16 & 7;
    const long sT = (long)(((tid & 7) ^ ((tid >> 3) & 7)) << 3);   // pre-swizzled slot (elements)
    const u16* sA = Ab + (ar0 + (tid >> 3)) * lda + ka0 + sT;
    const u16* sB = Bb + (br0 + (tid >> 3)) * ldb + kb0 + sT;
    u16* const ldsw = lds + wave * 512;
    // hoisted per-lane read bases (u16-element units)
    const int s0 = (quad ^ x) << 3;
    const int s1 = s0 ^ 32;
    const int aB0 = waveM * 8192 + l16 * 64 + s0;
    const int aB1 = waveM * 8192 + l16 * 64 + s1;
    const int bB0 = 32768 + (waveN >> 1) * 8192 + ((waveN & 1) * 64 + l16) * 64 + s0;
    const int bB1 = 32768 + (waveN >> 1) * 8192 + ((waveN & 1) * 64 + l16) * 64 + s1;

#define STG_A(p, mh, t) do { \
        const u16* g_ = sA + ((long)((mh) * 128)) * lda + (long)(t) * 64; \
        __builtin_amdgcn_global_load_lds((gas_t)g_, (las_t)(ldsw + (p) * 16384 + (mh) * 8192), 16, 0, 0); \
        __builtin_amdgcn_global_load_lds((gas_t)(g_ + 64 * lda), (las_t)(ldsw + (p) * 16384 + (mh) * 8192 + 4096), 16, 0, 0); \
    } while (0)
#define STG_B(p, nh, t) do { \
        const u16* g_ = sB + ((long)((nh) * 128)) * ldb + (long)(t) * 64; \
        __builtin_amdgcn_global_load_lds((gas_t)g_, (las_t)(ldsw + 32768 + (p) * 16384 + (nh) * 8192), 16, 0, 0); \
        __builtin_amdgcn_global_load_lds((gas_t)(g_ + 64 * ldb), (las_t)(ldsw + 32768 + (p) * 16384 + (nh) * 8192 + 4096), 16, 0, 0); \
    } while (0)
#define RD_A(mi_, ks_) (*(const bf16x8*)(lds + pb + ((ks_) ? aB1 : aB0) + (mi_) * 1024))
#define RD_B(ni_, ks_) (*(const bf16x8*)(lds + pb + ((ks_) ? bB1 : bB0) + (ni_) * 1024))

    // prologue: tile0 fully + tile1 {A0,B0}; wait tile0 resident (2 half-tiles stay in flight)
    STG_A(0, 0, 0); STG_A(0, 1, 0); STG_B(0, 0, 0); STG_B(0, 1, 0);
    if (ktiles > 1) {
        STG_A(1, 0, 1); STG_B(1, 0, 1);
        asm volatile("s_waitcnt vmcnt(4)" ::: "memory");
    } else {
        asm volatile("s_waitcnt vmcnt(0)" ::: "memory");
    }
    __builtin_amdgcn_s_barrier();

    bf16x8 aF[8][2], bF[2][2];
    for (int t = 0; t < ktiles; ++t) {
        const int p = t & 1, q = p ^ 1;
        const int pb = p * 16384;
        // ---- P1: read A rows[0,64) of wave band + B cols[0,32); issue (t+1,B1); MFMA quad(0,0)
#pragma unroll
        for (int mi = 0; mi < 4; ++mi)
#pragma unroll
            for (int ks = 0; ks < 2; ++ks) aF[mi][ks] = RD_A(mi, ks);
#pragma unroll
        for (int ni = 0; ni < 2; ++ni)
#pragma unroll
            for (int ks = 0; ks < 2; ++ks) bF[ni][ks] = RD_B(ni, ks);
        if (t + 1 < ktiles) STG_B(q, 1, t + 1);
        __builtin_amdgcn_s_barrier();
        __builtin_amdgcn_s_setprio(1);
#pragma unroll
        for (int mi = 0; mi < 4; ++mi)
#pragma unroll
            for (int ni = 0; ni < 2; ++ni)
#pragma unroll
                for (int ks = 0; ks < 2; ++ks)
                    acc[mi][ni] = __builtin_amdgcn_mfma_f32_16x16x32_bf16(aF[mi][ks], bF[ni][ks], acc[mi][ni], 0, 0, 0);
        __builtin_amdgcn_s_setprio(0);
        asm volatile("s_waitcnt lgkmcnt(0)" ::: "memory");   // reads drained before end barrier
        __builtin_amdgcn_s_barrier();
        // ---- P2: read A rows[64,128); issue (t+1,A1); MFMA quad(1,0)
#pragma unroll
        for (int mi = 4; mi < 8; ++mi)
#pragma unroll
            for (int ks = 0; ks < 2; ++ks) aF[mi][ks] = RD_A(mi, ks);
        if (t + 1 < ktiles) STG_A(q, 1, t + 1);
        __builtin_amdgcn_s_barrier();
        __builtin_amdgcn_s_setprio(1);
#pragma unroll
        for (int mi = 0; mi < 4; ++mi)
#pragma unroll
            for (int ni = 0; ni < 2; ++ni)
#pragma unroll
                for (int ks = 0; ks < 2; ++ks)
                    acc[4 + mi][ni] = __builtin_amdgcn_mfma_f32_16x16x32_bf16(aF[4 + mi][ks], bF[ni][ks], acc[4 + mi][ni], 0, 0, 0);
        __builtin_amdgcn_s_setprio(0);
        asm volatile("s_waitcnt lgkmcnt(0)" ::: "memory");
        __builtin_amdgcn_s_barrier();
        // ---- P3: read B cols[32,64); issue (t+2,A0); MFMA quad(0,1)
#pragma unroll
        for (int ni = 0; ni < 2; ++ni)
#pragma unroll
            for (int ks = 0; ks < 2; ++ks) bF[ni][ks] = RD_B(ni + 2, ks);
        if (t + 2 < ktiles) STG_A(p, 0, t + 2);
        __builtin_amdgcn_s_barrier();
        __builtin_amdgcn_s_setprio(1);
#pragma unroll
        for (int mi = 0; mi < 4; ++mi)
#pragma unroll
            for (int ni = 0; ni < 2; ++ni)
#pragma unroll
                for (int ks = 0; ks < 2; ++ks)
                    acc[mi][2 + ni] = __builtin_amdgcn_mfma_f32_16x16x32_bf16(aF[mi][ks], bF[ni][ks], acc[mi][2 + ni], 0, 0, 0);
        __builtin_amdgcn_s_setprio(0);
        asm volatile("s_waitcnt lgkmcnt(0)" ::: "memory");
        __builtin_amdgcn_s_barrier();
        // ---- P4: issue (t+2,B0); MFMA quad(1,1); counted vmcnt; barrier
        if (t + 2 < ktiles) STG_B(p, 0, t + 2);
        __builtin_amdgcn_s_setprio(1);
#pragma unroll
        for (int mi = 0; mi < 4; ++mi)
#pragma unroll
            for (int ni = 0; ni < 2; ++ni)
#pragma unroll
                for (int ks = 0; ks < 2; ++ks)
                    acc[4 + mi][2 + ni] = __builtin_amdgcn_mfma_f32_16x16x32_bf16(aF[4 + mi][ks], bF[ni][ks], acc[4 + mi][2 + ni], 0, 0, 0);
        __builtin_amdgcn_s_setprio(0);
        if (t + 2 < ktiles)      asm volatile("s_waitcnt vmcnt(4)" ::: "memory");
        else if (t + 1 < ktiles) asm volatile("s_waitcnt vmcnt(0)" ::: "memory");
        __builtin_amdgcn_s_barrier();
    }
#undef STG_A
#undef STG_B
#undef RD_A
#undef RD_B
}

// ---------------- tiled weight transpose (coalesced reads) ----------------
__global__ __launch_bounds__(256) void k_transw(const void* __restrict__ wqkv, const void* __restrict__ wgate,
                                                const void* __restrict__ wproj, const int* __restrict__ flag,
                                                u16* __restrict__ Wt, u16* __restrict__ WpT) {
    const int bid = blockIdx.x, tid = threadIdx.x;   // 1280 blocks: 80 n-tiles x 16 k-tiles
    const int ktl = bid & 15, ntile = bid >> 4;
    const int n0 = ntile * 64, k0 = ktl * 64;
    const int fl = flag[0];
    const void* src; int ld, c0;
    if (n0 < 3072)      { src = wqkv;  ld = 3072; c0 = n0; }
    else if (n0 < 4096) { src = wgate; ld = 1024; c0 = n0 - 3072; }
    else                { src = wproj; ld = 1024; c0 = n0 - 4096; }
    __shared__ u16 t[64][66];
#pragma unroll
    for (int i = 0; i < 16; ++i) {
        int idx = tid + i * 256; int r = idx >> 6, c = idx & 63;   // r=k, c=n (local)
        long off = (long)(k0 + r) * ld + c0 + c;
        float v = fl ? ((const float*)src)[off] : bf2f(((const u16*)src)[off]);
        t[r][c] = f2bf(v);
    }
    __syncthreads();
#pragma unroll
    for (int i = 0; i < 16; ++i) {
        int idx = tid + i * 256; int r = idx >> 6, c = idx & 63;   // r=n, c=k (local)
        int n = n0 + r;
        if (n < 4096) Wt[(long)n * 1024 + k0 + c] = t[c][r];
        else          WpT[(long)(n - 4096) * 1024 + k0 + c] = t[c][r];
    }
}

// ---------------- LayerNorm ----------------
__global__ __launch_bounds__(256) void k_ln(const void* __restrict__ xin, const u16* __restrict__ cv,
                                            const int* __restrict__ flag, u16* __restrict__ XN) {
    const long t = blockIdx.x; const int tid = threadIdx.x;
    const int fl = flag[0];
    float v[4], s = 0.f, sq = 0.f;
#pragma unroll
    for (int i = 0; i < 4; ++i) {
        long a = t * 1024 + tid + i * 256;
        v[i] = fl ? ((const float*)xin)[a] : bf2f(((const u16*)xin)[a]);
        s += v[i]; sq += v[i] * v[i];
    }
    for (int off = 32; off; off >>= 1) { s += __shfl_down(s, off, 64); sq += __shfl_down(sq, off, 64); }
    __shared__ float red[8];
    int lane = tid & 63, w = tid >> 6;
    if (!lane) { red[w] = s; red[4 + w] = sq; }
    __syncthreads();
    float S = red[0] + red[1] + red[2] + red[3];
    float SQ = red[4] + red[5] + red[6] + red[7];
    float mu = S * (1.f / 1024.f);
    float var = SQ * (1.f / 1024.f) - mu * mu;
    float rs = rsqrtf(var + 1e-5f);
#pragma unroll
    for (int i = 0; i < 4; ++i) {
        int col = tid + i * 256;
        XN[t * 1024 + col] = f2bf((v[i] - mu) * rs * bf2f(cv[5120 + col]) + bf2f(cv[6144 + col]));
    }
}

// ---------------- GEMM1 (256^2 8-phase): [q|k|v|gate] = XN @ Wt^T + bias ----------------
// grid 1024 = 64 mt x 16 nt; group = nt>>2: 0=q(elu+1) 1=k 2=v(transposed) 3=gate
__global__ __launch_bounds__(512, 2) void k_gemm1(const u16* __restrict__ XN, const u16* __restrict__ Wt,
                                                  const u16* __restrict__ cv,
                                                  u16* __restrict__ Q, u16* __restrict__ K,
                                                  u16* __restrict__ G, u16* __restrict__ vT) {
    __shared__ u16 lds[65536];   // 128KB: K-loop dbuf; reused as [64][264] transpose staging for v
    const int tid = threadIdx.x;
    const int swz = ((blockIdx.x & 7) << 7) | (blockIdx.x >> 3);   // bijective XCD swizzle (1024%8==0)
    const int nt = swz & 15, mt = swz >> 4;
    f32x4 acc[8][4]; ZERO_ACC8(acc);
    gemm256_loop(XN, (long)mt * 256, 1024, 0, Wt, (long)nt * 256, 1024, 0, 16, lds, tid, acc);
    const int lane = tid & 63, wave = tid >> 6;
    const int waveM = wave >> 2, waveN = wave & 3;
    const int l16 = lane & 15, quad = lane >> 4;
    const int g = nt >> 2;
    if (g == 2) {              // v: stage [col][264] in LDS, write t-contiguous to vT[b][d][t]
        const int b = mt >> 4;
        const long tb0 = (long)(mt & 15) * 256;
#pragma unroll
        for (int h = 0; h < 4; ++h) {
            if (waveN == h) {
#pragma unroll
                for (int mi = 0; mi < 8; ++mi)
#pragma unroll
                    for (int ni = 0; ni < 4; ++ni) {
                        int col = ni * 16 + l16;
                        float bias = bf2f(cv[nt * 256 + h * 64 + col]);
#pragma unroll
                        for (int r = 0; r < 4; ++r)
                            lds[col * 264 + waveM * 128 + mi * 16 + quad * 4 + r] = f2bf(acc[mi][ni][r] + bias);
                    }
            }
            __syncthreads();
#pragma unroll
            for (int i = 0; i < 4; ++i) {
                int c = tid + i * 512;                  // 2048 chunks of 8 u16
                int col = c >> 5, t8 = (c & 31) * 8;
                uint4 val = *(const uint4*)(lds + col * 264 + t8);
                long dg = (long)(nt & 3) * 256 + h * 64 + col;
                *(uint4*)(vT + (long)b * 4194304 + dg * 4096 + tb0 + t8) = val;
            }
            __syncthreads();
        }
    } else {
        u16* dst = (g == 0) ? Q : (g == 1) ? K : G;
#pragma unroll
        for (int mi = 0; mi < 8; ++mi)
#pragma unroll
            for (int ni = 0; ni < 4; ++ni) {
                int colg = nt * 256 + waveN * 64 + ni * 16 + l16;
                int d = colg & 1023;
                float bias = bf2f(cv[colg]);
                long row0 = (long)mt * 256 + waveM * 128 + mi * 16 + quad * 4;
#pragma unroll
                for (int r = 0; r < 4; ++r) {
                    float v = acc[mi][ni][r] + bias;
                    if (g == 0) v = v > 0.f ? v + 1.f : expf(v);   // elu(q)+1 fused, f32
                    dst[(row0 + r) * 1024 + d] = f2bf(v);
                }
            }
    }
}

// ---- fused: k = elu(k_raw*sigmoid(gate))+1 in place; kT[b][d][t] transpose; csum atomics ----
// grid 4096 = 256 tt x 16 dt; replaces k_act + k_transk + k_csum (one pass over K,G).
// kT gets a DEDICATED 32MB region (no alias) -- cross-block read/write overlap audit in r6.
__global__ __launch_bounds__(256) void k_actk(u16* __restrict__ K, const u16* __restrict__ G,
                                              u16* __restrict__ kT, float* __restrict__ csum) {
    const int bid = blockIdx.x, tid = threadIdx.x;
    const int dt = bid & 15, tt = bid >> 4;
    __shared__ u16 tileS[64][65];
#pragma unroll
    for (int i = 0; i < 16; ++i) {
        int idx = tid + i * 256; int r = idx >> 6, cc = idx & 63;
        long a = (long)(tt * 64 + r) * 1024 + dt * 64 + cc;
        float kk = bf2f(K[a]) / (1.f + expf(-bf2f(G[a])));
        kk = kk > 0.f ? kk + 1.f : expf(kk);
        u16 v = f2bf(kk);
        K[a] = v;
        tileS[r][cc] = v;
    }
    __syncthreads();
    long tg = (long)tt * 64; int b = (int)(tg >> 12); long tb = tg & 4095;
    int c = (int)((tg >> 10) & 3);
#pragma unroll
    for (int i = 0; i < 16; ++i) {
        int idx = tid + i * 256; int r = idx >> 6, cc = idx & 63;
        kT[(long)b * 4194304 + (long)(dt * 64 + r) * 4096 + tb + cc] = tileS[cc][r];
    }
    if (tid < 64) {        // per-column partial sums over the 64 t-rows of this tile
        float s = 0.f;
#pragma unroll
        for (int r = 0; r < 64; ++r) s += bf2f(tileS[r][tid]);
        atomicAdd(&csum[((b * 4 + c) << 10) + dt * 64 + tid], s);
    }
}

// ---------------- pass1 (256^2 8-phase): ST[b][c][d][e] = sum_s v[s,d] k[s,e] ----------------
// grid 256 = 16 bc (LOW bits -> same-bc blocks share an XCD L2) x 16 tiles(4dt x 4et)
__global__ __launch_bounds__(512, 2) void k_pass1(const u16* __restrict__ kT, const u16* __restrict__ vT,
                                                  u16* __restrict__ ST) {
    __shared__ u16 lds[65536];
    const int tid = threadIdx.x, bid = blockIdx.x;
    const int bc = bid & 15, tile = bid >> 4;
    const int dt = tile >> 2, et = tile & 3;
    const int c = bc & 3, b = bc >> 2;
    f32x4 acc[8][4]; ZERO_ACC8(acc);
    gemm256_loop(vT + (long)b * 4194304, (long)dt * 256, 4096, (long)c * 1024,
                 kT + (long)b * 4194304, (long)et * 256, 4096, (long)c * 1024, 16, lds, tid, acc);
    const int lane = tid & 63, wave = tid >> 6;
    const int waveM = wave >> 2, waveN = wave & 3;
    const int l16 = lane & 15, quad = lane >> 4;
    u16* dst = ST + ((long)(b * 4 + c) << 20);
#pragma unroll
    for (int mi = 0; mi < 8; ++mi)
#pragma unroll
        for (int ni = 0; ni < 4; ++ni) {
            long e = et * 256 + waveN * 64 + ni * 16 + l16;
            long d0 = dt * 256 + waveM * 128 + mi * 16 + quad * 4;
#pragma unroll
            for (int r = 0; r < 4; ++r)
                dst[(d0 + r) * 1024 + e] = f2bf(acc[mi][ni][r]);
        }
}

// ---------------- in-place exclusive prefix over chunk states ----------------
__global__ __launch_bounds__(256) void k_stpre(u16* __restrict__ ST) {
    const long gid = (long)blockIdx.x * 256 + threadIdx.x;  // 4M
    const int b = (int)(gid >> 20); const long rem = gid & 0xFFFFF;
    float run = 0.f;
    for (int c = 0; c < 4; ++c) {
        long a = (((long)(b * 4 + c)) << 20) + rem;
        float v = bf2f(ST[a]);
        ST[a] = f2bf(run);
        run += v;
    }
}

// ---------------- pass2a (256^2 8-phase): P[t, s_local] = masked q_t . k_s (intra chunk) ----
// grid 256 = 16 bc x 16 tiles(4tt x 4ss); ss>tt tiles are zero-filled
__global__ __launch_bounds__(512, 2) void k_pass2a(const u16* __restrict__ Q, const u16* __restrict__ K,
                                                   u16* __restrict__ P) {
    __shared__ u16 lds[65536];
    const int tid = threadIdx.x, bid = blockIdx.x;
    const int bc = bid & 15, tile = bid >> 4;
    const int tt = tile >> 2, ss = tile & 3;
    const int c = bc & 3, b = bc >> 2;
    const long trow0 = (long)b * 4096 + c * 1024 + tt * 256;
    if (ss > tt) {   // strictly-upper 256x256 tile: zeros (block-uniform)
#pragma unroll
        for (int i = 0; i < 16; ++i) {
            int ch = tid + i * 512;                 // 8192 chunks of 8 u16
            int row = ch >> 5, col8 = (ch & 31) * 8;
            *(uint4*)(P + (trow0 + row) * 1024 + ss * 256 + col8) = (uint4){0u, 0u, 0u, 0u};
        }
        return;
    }
    const long srow0 = (long)b * 4096 + c * 1024 + ss * 256;
    f32x4 acc[8][4]; ZERO_ACC8(acc);
    gemm256_loop(Q, trow0, 1024, 0, K, srow0, 1024, 0, 16, lds, tid, acc);
    const int lane = tid & 63, wave = tid >> 6;
    const int waveM = wave >> 2, waveN = wave & 3;
    const int l16 = lane & 15, quad = lane >> 4;
    const int diag = (ss == tt);
#pragma unroll
    for (int mi = 0; mi < 8; ++mi)
#pragma unroll
        for (int ni = 0; ni < 4; ++ni) {
            int slc = waveN * 64 + ni * 16 + l16;
#pragma unroll
            for (int r = 0; r < 4; ++r) {
                int tl = waveM * 128 + mi * 16 + quad * 4 + r;
                float v = (!diag || tl >= slc) ? acc[mi][ni][r] : 0.f;
                P[(trow0 + tl) * 1024 + ss * 256 + slc] = f2bf(v);
            }
        }
}

// ---------------- den[t] = q_t . chunk_prefix + rowsum(P) + eps ----------------
__global__ __launch_bounds__(256) void k_den(const u16* __restrict__ Q, const u16* __restrict__ P,
                                             const float* __restrict__ csum, float* __restrict__ den) {
    const long t = blockIdx.x; const int tid = threadIdx.x;
    const int b = (int)(t >> 12), c = (int)((t >> 10) & 3);
    float s = 0.f;
#pragma unroll
    for (int i = 0; i < 4; ++i) {
        int e = tid + i * 256;
        float kp = 0.f;
        for (int cp = 0; cp < c; ++cp) kp += csum[((b * 4 + cp) << 10) + e];
        s += bf2f(Q[t * 1024 + e]) * kp + bf2f(P[t * 1024 + e]);
    }
    for (int off = 32; off; off >>= 1) s += __shfl_down(s, off, 64);
    __shared__ float red[4];
    int lane = tid & 63, w = tid >> 6;
    if (!lane) red[w] = s;
    __syncthreads();
    if (!tid) den[t] = red[0] + red[1] + red[2] + red[3] + 1e-6f;
}

// ---------------- pass2b (256^2 8-phase): y[t,d] = (q@ST_prefix + P@V)/den ----------------
// grid 256 = 16 bc x 16 tiles(4tt x 4dd)
__global__ __launch_bounds__(512, 2) void k_pass2b(const u16* __restrict__ Q, const u16* __restrict__ ST,
                                                   const u16* __restrict__ P, const u16* __restrict__ vT,
                                                   const float* __restrict__ den, u16* __restrict__ Yb) {
    __shared__ u16 lds[65536];
    const int tid = threadIdx.x, bid = blockIdx.x;
    const int bc = bid & 15, tile = bid >> 4;
    const int tt = tile >> 2, dd = tile & 3;
    const int c = bc & 3, b = bc >> 2;
    const long trow0 = (long)b * 4096 + c * 1024 + tt * 256;
    f32x4 acc[8][4]; ZERO_ACC8(acc);
    if (c > 0)  // inter-chunk (prefix is zero for c==0); block-uniform branch
        gemm256_loop(Q, trow0, 1024, 0, ST + ((long)(b * 4 + c) << 20), (long)dd * 256, 1024, 0,
                     16, lds, tid, acc);
    // intra-chunk: P upper region zeroed, so full tiles up to (tt+1)*256 of s are correct
    gemm256_loop(P, trow0, 1024, 0, vT + (long)b * 4194304, (long)dd * 256, 4096, (long)c * 1024,
                 (tt + 1) * 4, lds, tid, acc);
    const int lane = tid & 63, wave = tid >> 6;
    const int waveM = wave >> 2, waveN = wave & 3;
    const int l16 = lane & 15, quad = lane >> 4;
#pragma unroll
    for (int mi = 0; mi < 8; ++mi)
#pragma unroll
        for (int ni = 0; ni < 4; ++ni) {
            long d = dd * 256 + waveN * 64 + ni * 16 + l16;
#pragma unroll
            for (int r = 0; r < 4; ++r) {
                long t = trow0 + waveM * 128 + mi * 16 + quad * 4 + r;
                Yb[t * 1024 + d] = f2bf(acc[mi][ni][r] / den[t]);
            }
        }
}

// ---------------- proj (256^2 8-phase): out = y @ w_proj + b_proj (dtype-aware store) ----------------
// grid 256 = 64 mt x 4 nt
__global__ __launch_bounds__(512, 2) void k_proj(const u16* __restrict__ Yb, const u16* __restrict__ WpT,
                                                 const u16* __restrict__ cv, const int* __restrict__ flag,
                                                 void* __restrict__ out) {
    __shared__ u16 lds[65536];
    const int tid = threadIdx.x, bid = blockIdx.x;
    const int nt = bid & 3, mt = bid >> 2;
    f32x4 acc[8][4]; ZERO_ACC8(acc);
    gemm256_loop(Yb, (long)mt * 256, 1024, 0, WpT, (long)nt * 256, 1024, 0, 16, lds, tid, acc);
    const int lane = tid & 63, wave = tid >> 6;
    const int waveM = wave >> 2, waveN = wave & 3;
    const int l16 = lane & 15, quad = lane >> 4;
    const int fl = flag[0];
#pragma unroll
    for (int mi = 0; mi < 8; ++mi)
#pragma unroll
        for (int ni = 0; ni < 4; ++ni) {
            long col = nt * 256 + waveN * 64 + ni * 16 + l16;
            float bias = bf2f(cv[4096 + col]);
            long row0 = (long)mt * 256 + waveM * 128 + mi * 16 + quad * 4;
#pragma unroll
            for (int r = 0; r < 4; ++r) {
                float v = acc[mi][ni][r] + bias;
                if (fl) ((float*)out)[(row0 + r) * 1024 + col] = v;
                else    ((u16*)out)[(row0 + r) * 1024 + col] = f2bf(v);
            }
        }
}

// ---------------- fallback: report ws_size via output constant ----------------
__global__ __launch_bounds__(256) void k_fb(u16* __restrict__ out, long n, float val) {
    long i = (long)blockIdx.x * 256 + threadIdx.x;
    if (i < n) out[i] = f2bf(val);
}

extern "C" void kernel_launch(void* const* d_in, const int* in_sizes, int n_in,
                              void* d_out, int out_size, void* d_ws, size_t ws_size,
                              hipStream_t stream) {
    const void* x     = d_in[0];
    const void* wqkv  = d_in[1];
    const void* bqkv  = d_in[2];
    const void* wgate = d_in[3];
    const void* bgate = d_in[4];
    const void* wproj = d_in[5];
    const void* bproj = d_in[6];
    const void* lng   = d_in[7];
    const void* lnb   = d_in[8];

    const long NEEDED = 211959808L;   // ~202.1 MB (adds dedicated 32MB kT region)
    const long NEEDED_OLD = 178403336L;
    if (ws_size < (size_t)NEEDED) {
        k_fb<<<(int)((out_size + 255) / 256), 256, 0, stream>>>((u16*)d_out, out_size,
                                                                 (float)(ws_size >> 20));
        (void)NEEDED_OLD;
        return;
    }

    char* w = (char*)d_ws;
    u16* XN  = (u16*)(w);                 // 32MB [16384,1024]; dead after gemm1
    u16* ST  = XN;                        // 32MB [16][1024][1024] (alias)
    u16* Q   = (u16*)(w + 33554432L);     // 32MB (elu(q)+1)
    u16* K   = (u16*)(w + 67108864L);     // 32MB; dead after pass2a
    u16* Yb  = K;                         // 32MB (alias)
    u16* G   = (u16*)(w + 100663296L);    // 32MB gate; dead after actk
    u16* P   = G;                         // (alias; P written by pass2a after actk)
    u16* vT  = (u16*)(w + 134217728L);    // 32MB [4][1024][4096]
    u16* Wt  = (u16*)(w + 167772160L);    // 8MB  [4096,1024]
    u16* WpT = (u16*)(w + 176160768L);    // 2MB  [1024,1024]
    float* csum = (float*)(w + 178257920L);  // 64KB [16][1024]
    float* den  = (float*)(w + 178323456L);  // 64KB [16384]
    u16* cv     = (u16*)(w + 178388992L);    // 14KB
    int* flag   = (int*)(w + 178403328L);    // 4B
    u16* kT     = (u16*)(w + 178405376L);    // 32MB dedicated [4][1024][4096]; dead after pass1

    k_detect<<<1,     256, 0, stream>>>((const u16*)wqkv, flag);
    k_cvec  <<<92,    256, 0, stream>>>(bqkv, bgate, bproj, lng, lnb, flag, cv, csum);
    k_transw<<<1280,  256, 0, stream>>>(wqkv, wgate, wproj, flag, Wt, WpT);
    k_ln    <<<16384, 256, 0, stream>>>(x, cv, flag, XN);
    k_gemm1 <<<1024,  512, 0, stream>>>(XN, Wt, cv, Q, K, G, vT);
    k_actk  <<<4096,  256, 0, stream>>>(K, G, kT, csum);
    k_pass1 <<<256,   512, 0, stream>>>(kT, vT, ST);
    k_stpre <<<16384, 256, 0, stream>>>(ST);
    k_pass2a<<<256,   512, 0, stream>>>(Q, K, P);
    k_den   <<<16384, 256, 0, stream>>>(Q, P, csum, den);
    k_pass2b<<<256,   512, 0, stream>>>(Q, ST, P, vT, den, Yb);
    k_proj  <<<256,   512, 0, stream>>>(Yb, WpT, cv, flag, d_out);
}